// Round 4
// baseline (532.907 us; speedup 1.0000x reference)
//
#include <hip/hip_runtime.h>
#include <hip/hip_bf16.h>
#include <cstddef>

// Problem constants
#define BB    8
#define CIN   64
#define HH    256
#define WW    256
#define NN    65536            // H*W per batch
#define NP    (BB*NN)          // total pixels = 524288
#define QC    64               // q channels = HEADS*QD
#define KC    16               // k channels = QD*U
#define VC    32               // v channels = VD*U
#define HEADS 4
#define QD    16

// fp32 scratch (float-element offsets within ws)
#define BQ_OFF 7168            // 64
#define BV_OFF 7232            // 32
#define WP_OFF 7264            // 16*9
#define BP_OFF 7408            // 16
#define S_OFF  7424            // B*KC softmax denominators (final)
#define M_OFF  7552            // B*KC*VC numerators (final)
#define FLAG_OFF 12000         // int flag: 1 = inputs are fp32, 0 = bf16
#define WSW_BYTE 49152         // bf16 fragment-swizzled W: 7168 ushorts (14336 B)
#define BF_BASE 65536          // byte offset where bf16 staging starts
#define NCHUNK 128             // k_lamc chunks per batch

typedef __hip_bfloat16 bf16;
typedef __attribute__((ext_vector_type(8))) short short8;   // 8 bf16 (4 VGPRs)
typedef __attribute__((ext_vector_type(4))) short short4v;  // 4 bf16 (8B store)
typedef __attribute__((ext_vector_type(4))) float f32x4;    // MFMA C/D

#define MFMA16(a, b, c) __builtin_amdgcn_mfma_f32_16x16x32_bf16((a), (b), (c), 0, 0, 0)

__device__ __forceinline__ short f2bf_s(float f) {
    bf16 h = (bf16)f;
    return __builtin_bit_cast(short, h);
}
__device__ __forceinline__ float bf2f(short u) {
    unsigned x = ((unsigned)(unsigned short)u) << 16;
    return __builtin_bit_cast(float, x);
}

// ---------------- K-1: detect input dtype --------------------------------
__global__ void k_detect(const unsigned short* __restrict xu, int* __restrict flag) {
    if (threadIdx.x == 0 && blockIdx.x == 0) {
        int big = 0, zero = 0;
        for (int i = 0; i < 256; ++i) {
            unsigned short u = xu[i];
            int e = (u >> 7) & 0xFF;
            big  += (e >= 134);
            zero += (u == 0);
        }
        *flag = (big > 4 || zero > 64) ? 1 : 0;
    }
}

__device__ __forceinline__ float ldin(const void* p, int i, int isf) {
    return isf ? ((const float*)p)[i] : (float)(((const bf16*)p)[i]);
}

// ---------------- K0: weight prep ------------------------------------------
// Writes W BN-folded, bf16, in MFMA A-fragment order:
//   wsw[((mt*2+kh)*64 + lane)*8 + i] = W[mt*16 + (lane&15)][kh*32 + (lane>>4)*8 + i]
// so k_qkv's A-setup is 14 dwordx4 loads instead of ~250 scalar ops.
__global__ void k_prep(const void* __restrict wq, const void* __restrict gq,
                       const void* __restrict bq, const void* __restrict wk,
                       const void* __restrict wv, const void* __restrict gv,
                       const void* __restrict bv, const void* __restrict wp,
                       const void* __restrict bp, float* __restrict wf,
                       const int* __restrict flag) {
    int t = threadIdx.x;
    int isf = *flag;
    float rs = rsqrtf(1.0f + 1e-5f);
    unsigned short* wsw = (unsigned short*)((char*)wf + WSW_BYTE);
    for (int idx = t; idx < 7168; idx += 256) {
        int i = idx & 7, lane = (idx >> 3) & 63, blk = idx >> 9;
        int kh = blk & 1, mt = blk >> 1;
        int m = lane & 15, g = lane >> 4;
        int row = mt * 16 + m, col = kh * 32 + g * 8 + i;
        float v;
        if (row < 64)      v = ldin(wq, row * 64 + col, isf) * (ldin(gq, row, isf) * rs);
        else if (row < 80) v = ldin(wk, (row - 64) * 64 + col, isf);
        else               v = ldin(wv, (row - 80) * 64 + col, isf)
                             * (ldin(gv, row - 80, isf) * rs);
        wsw[idx] = (unsigned short)f2bf_s(v);
    }
    for (int i = t; i < 64;  i += 256) wf[BQ_OFF + i] = ldin(bq, i, isf);
    for (int i = t; i < 32;  i += 256) wf[BV_OFF + i] = ldin(bv, i, isf);
    for (int i = t; i < 144; i += 256) wf[WP_OFF + i] = ldin(wp, i, isf);
    for (int i = t; i < 16;  i += 256) wf[BP_OFF + i] = ldin(bp, i, isf);
}

// ---------------- K1: q / exp(k) / v via MFMA ------------------------------
// GEMM: out[112][p] = W[112][64] * x[64][p]. A (weights) in VGPRs via 14
// dwordx4 loads of the pre-swizzled bf16 W; B (x) direct from global in
// fragment order. TPW=4 amortizes setup; q -> [pix][64], ek/v -> [ch][pix].
#define TPW 4                      // 16-px tiles per wave
__global__ __launch_bounds__(256) void k_qkv(const void* __restrict x,
        const float* __restrict wf, const int* __restrict flag,
        bf16* __restrict qws2, bf16* __restrict ekws, bf16* __restrict vws) {
    const int lane = threadIdx.x & 63;
    const int m = lane & 15, g = lane >> 4;       // frag col / lane-group
    const int wave = blockIdx.x * 4 + (threadIdx.x >> 6);
    const int px0 = wave * (TPW * 16);            // 64 px per wave, batch-aligned
    const int b = px0 >> 16;
    const int n0 = px0 & 0xFFFF;
    const int isf = *flag;                        // wave-uniform

    // --- A-fragments: 14 vector loads from the pre-swizzled W ---
    const unsigned short* wsw = (const unsigned short*)((const char*)wf + WSW_BYTE);
    short8 a[7][2];
    #pragma unroll
    for (int mt = 0; mt < 7; ++mt)
        #pragma unroll
        for (int kh = 0; kh < 2; ++kh)
            a[mt][kh] = *(const short8*)(wsw + ((mt * 2 + kh) * 64 + lane) * 8);

    // --- bias as MFMA C-init: C[row=oc][col=px], row = g*4 + r ---
    f32x4 bias[7];
    #pragma unroll
    for (int mt = 0; mt < 4; ++mt)
        bias[mt] = *(const f32x4*)(wf + BQ_OFF + mt * 16 + g * 4);
    bias[4] = (f32x4){0.f, 0.f, 0.f, 0.f};        // k has no bias
    #pragma unroll
    for (int mt = 5; mt < 7; ++mt)
        bias[mt] = *(const f32x4*)(wf + BV_OFF + (mt - 5) * 16 + g * 4);

    #pragma unroll
    for (int it = 0; it < TPW; ++it) {
        const int n = n0 + it * 16 + m;
        const size_t p = (size_t)px0 + it * 16 + m;

        // --- B-fragments direct from global: lane reads c = kh*32+g*8+i at
        //     pixel n; per (i,kh) each 16-lane group covers a contiguous run.
        short8 bf0, bf1;
        if (isf) {
            const float* xp = (const float*)x + (size_t)b * CIN * NN
                            + (size_t)g * 8 * NN + n;
            #pragma unroll
            for (int i = 0; i < 8; ++i) bf0[i] = f2bf_s(xp[(size_t)i * NN]);
            #pragma unroll
            for (int i = 0; i < 8; ++i) bf1[i] = f2bf_s(xp[(size_t)(32 + i) * NN]);
        } else {
            const unsigned short* xp = (const unsigned short*)x + (size_t)b * CIN * NN
                                     + (size_t)g * 8 * NN + n;
            #pragma unroll
            for (int i = 0; i < 8; ++i) bf0[i] = (short)xp[(size_t)i * NN];
            #pragma unroll
            for (int i = 0; i < 8; ++i) bf1[i] = (short)xp[(size_t)(32 + i) * NN];
        }

        f32x4 acc[7];
        #pragma unroll
        for (int mt = 0; mt < 7; ++mt) {
            acc[mt] = MFMA16(a[mt][0], bf0, bias[mt]);
            acc[mt] = MFMA16(a[mt][1], bf1, acc[mt]);
        }

        // --- epilogue: D row = oc = mt*16 + g*4 + r, col = px (lane m) ---
        // q -> [pix][64]: 4 packed 8B stores
        bf16* qp = qws2 + p * 64;
        #pragma unroll
        for (int mt = 0; mt < 4; ++mt) {
            short4v pk;
            #pragma unroll
            for (int r = 0; r < 4; ++r) pk[r] = f2bf_s(acc[mt][r]);
            *(short4v*)(qp + mt * 16 + g * 4) = pk;
        }
        // ek -> [ch][pix]
        #pragma unroll
        for (int r = 0; r < 4; ++r)
            ekws[(size_t)(g * 4 + r) * NP + p] = (bf16)__expf(acc[4][r]);
        // v -> [ch][pix]
        #pragma unroll
        for (int mt = 0; mt < 2; ++mt)
            #pragma unroll
            for (int r = 0; r < 4; ++r)
                vws[(size_t)(mt * 16 + g * 4 + r) * NP + p] = (bf16)acc[5 + mt][r];
    }
}

// ---------------- K2: lam_c partials via MFMA (no atomics) -----------------
// Block (chunk, b) handles 512 px; per-block partial M[16][32], S[16] written
// to Mpart/Spart; k_reduce collapses the 128 chunks deterministically.
__global__ __launch_bounds__(256) void k_lamc(const bf16* __restrict ekws,
        const bf16* __restrict vws, float* __restrict Mpart,
        float* __restrict Spart) {
    __shared__ float MM[4][512];
    __shared__ float SS[4][16];
    const int b = blockIdx.y, chunk = blockIdx.x;
    const int t = threadIdx.x, w = t >> 6, lane = t & 63;
    const int m = lane & 15, g = lane >> 4;
    const size_t px0 = (size_t)b * NN + (size_t)chunk * 512 + (size_t)w * 128;

    f32x4 acc0 = {0.f, 0.f, 0.f, 0.f}, acc1 = {0.f, 0.f, 0.f, 0.f};
    float s = 0.0f;
    #pragma unroll
    for (int st = 0; st < 4; ++st) {
        const size_t p = px0 + st * 32 + g * 8;
        short8 afr = *(const short8*)(ekws + (size_t)m * NP + p);
        short8 b0  = *(const short8*)(vws + (size_t)m * NP + p);
        short8 b1  = *(const short8*)(vws + (size_t)(16 + m) * NP + p);
        acc0 = MFMA16(afr, b0, acc0);
        acc1 = MFMA16(afr, b1, acc1);
        #pragma unroll
        for (int i = 0; i < 8; ++i) s += bf2f(afr[i]);
    }
    s += __shfl_xor(s, 16);
    s += __shfl_xor(s, 32);
    if (g == 0) SS[w][m] = s;
    #pragma unroll
    for (int r = 0; r < 4; ++r) {
        MM[w][(g * 4 + r) * 32 + m]      = acc0[r];
        MM[w][(g * 4 + r) * 32 + 16 + m] = acc1[r];
    }
    __syncthreads();
    for (int i = t; i < 512; i += 256)
        Mpart[((size_t)b * NCHUNK + chunk) * 512 + i]
            = MM[0][i] + MM[1][i] + MM[2][i] + MM[3][i];
    if (t < 16)
        Spart[((size_t)b * NCHUNK + chunk) * 16 + t]
            = SS[0][t] + SS[1][t] + SS[2][t] + SS[3][t];
}

// ---------------- K2b: collapse partials -> Mg, Sg -------------------------
__global__ __launch_bounds__(256) void k_reduce(const float* __restrict Mpart,
        const float* __restrict Spart, float* __restrict Mg, float* __restrict Sg) {
    const int b = blockIdx.y, p = blockIdx.x, t = threadIdx.x;
    __shared__ float R[256];
    __shared__ float RS[128];
    const int e = t & 63, c4 = t >> 6;
    float a = 0.0f;
    for (int c = c4; c < NCHUNK; c += 4)
        a += Mpart[((size_t)b * NCHUNK + c) * 512 + p * 64 + e];
    R[t] = a;
    float s2 = 0.0f;
    if (p == 0 && t < 128) {
        int e2 = t & 15, c8 = t >> 4;
        for (int c = c8; c < NCHUNK; c += 8)
            s2 += Spart[((size_t)b * NCHUNK + c) * 16 + e2];
    }
    if (t < 128) RS[t] = s2;
    __syncthreads();
    if (t < 64) Mg[b * 512 + p * 64 + t] = R[t] + R[64 + t] + R[128 + t] + R[192 + t];
    if (p == 0 && t < 16)
        Sg[b * 16 + t] = RS[t] + RS[16 + t] + RS[32 + t] + RS[48 + t]
                       + RS[64 + t] + RS[80 + t] + RS[96 + t] + RS[112 + t];
}

// ---------------- K3: output = q·(lam_c+bp) + (q·Wp) * v-neighborhood -----
// Thread owns (pixel, head-pair): qf[32]. Block = 128 px x 2 head-groups;
// all 32 v-channels' 3-row windows staged once in LDS (single barrier).
__global__ __launch_bounds__(256) void k_out(const bf16* __restrict qws2,
        const bf16* __restrict vws, const float* __restrict wf,
        const float* __restrict Sg, const float* __restrict Mg,
        const int* __restrict flag, void* __restrict outv) {
    const int y = blockIdx.x >> 1, xh = blockIdx.x & 1, b = blockIdx.y;
    const int tid = threadIdx.x;
    const int pxl = tid & 127, hg = tid >> 7;     // local pixel / head-group
    const int px0 = xh * 128;
    const int isf = *flag;

    __shared__ float As[512];                     // [v][k] : lam_c + bp
    __shared__ float WPs[144];                    // Wp[k][9]
    __shared__ unsigned short VS[32 * 3 * 144];   // [ch][3 rows][144] bf16, x0@idx8

    for (int i = tid; i < 512; i += 256) {
        int k = i & 15, v = i >> 4;
        As[i] = Mg[b * 512 + k * 32 + v] / Sg[b * 16 + k] + wf[BP_OFF + k];
    }
    if (tid < 144) WPs[tid] = wf[WP_OFF + tid];

    // --- stage v: 32 ch x 3 rows x 144 px (window px0-8 .. px0+135) ---
    #pragma unroll
    for (int kk = 0; kk < 7; ++kk) {
        int idx = tid + kk * 256;                 // (c,j,i): 32*3*18 = 1728
        if (idx < 1728) {
            int c = idx / 54, rem = idx - c * 54;
            int j = rem / 18, i = rem - j * 18;
            int yy = y + j - 1;
            int x0 = px0 - 8 + i * 8;
            short8 val = {0, 0, 0, 0, 0, 0, 0, 0};
            if (yy >= 0 && yy < HH && x0 >= 0 && x0 <= WW - 8)
                val = *(const short8*)(vws + (size_t)c * NP + (size_t)b * NN
                                       + (size_t)yy * WW + x0);
            *(short8*)&VS[(c * 3 + j) * 144 + i * 8] = val;
        }
    }
    __syncthreads();

    // --- q for this thread's 2 heads (32 channels) ---
    const size_t pix = (size_t)b * NN + (size_t)y * WW + px0 + pxl;
    const short8* qrow = (const short8*)(qws2 + pix * 64) + hg * 4;
    float qf[32];
    #pragma unroll
    for (int j = 0; j < 4; ++j) {
        short8 qv = qrow[j];
        #pragma unroll
        for (int e = 0; e < 8; ++e) qf[j * 8 + e] = bf2f(qv[e]);
    }

    // g4[hl][t] = q[hl,:] . Wp[:,t]
    float g4[2][9];
    #pragma unroll
    for (int hl = 0; hl < 2; ++hl)
        #pragma unroll
        for (int tn = 0; tn < 9; ++tn) g4[hl][tn] = 0.0f;
    #pragma unroll
    for (int k = 0; k < 16; ++k)
        #pragma unroll
        for (int tn = 0; tn < 9; ++tn) {
            float w = WPs[k * 9 + tn];
            g4[0][tn] += qf[k] * w;
            g4[1][tn] += qf[16 + k] * w;
        }

    const size_t obase = ((size_t)(b * HEADS + hg * 2) * VC) * NN
                       + (size_t)y * WW + px0 + pxl;
    #pragma unroll 2
    for (int vc = 0; vc < VC; ++vc) {
        float vnf[9];
        const unsigned short* vb = &VS[vc * 3 * 144 + 7 + pxl];
        #pragma unroll
        for (int j = 0; j < 3; ++j)
            #pragma unroll
            for (int dx = 0; dx < 3; ++dx)
                vnf[j * 3 + dx] = bf2f((short)vb[j * 144 + dx]);
        float Ak[16];
        const f32x4* ap = (const f32x4*)&As[vc * 16];
        #pragma unroll
        for (int qq = 0; qq < 4; ++qq) {
            f32x4 a4 = ap[qq];
            #pragma unroll
            for (int e = 0; e < 4; ++e) Ak[qq * 4 + e] = a4[e];
        }
        #pragma unroll
        for (int hl = 0; hl < 2; ++hl) {
            float acc = 0.0f;
            #pragma unroll
            for (int k = 0; k < 16; ++k) acc += qf[hl * 16 + k] * Ak[k];
            #pragma unroll
            for (int tn = 0; tn < 9; ++tn) acc += g4[hl][tn] * vnf[tn];
            size_t idx2 = obase + ((size_t)hl * VC + vc) * NN;
            if (isf) ((float*)outv)[idx2] = acc;
            else     ((bf16*)outv)[idx2] = (bf16)acc;
        }
    }
}

extern "C" void kernel_launch(void* const* d_in, const int* in_sizes, int n_in,
                              void* d_out, int out_size, void* d_ws, size_t ws_size,
                              hipStream_t stream) {
    float* wf = (float*)d_ws;
    int* flag = (int*)wf + FLAG_OFF;
    bf16* qws2 = (bf16*)((char*)d_ws + BF_BASE);
    bf16* ekws = qws2 + (size_t)QC * NP;
    bf16* vws  = ekws + (size_t)KC * NP;
    float* Mpart = (float*)((char*)d_ws + BF_BASE + (size_t)(QC + KC + VC) * NP * 2);
    float* Spart = Mpart + (size_t)BB * NCHUNK * 512;
    // ws usage: 65536 + 112*524288*2 + (8*128*512 + 8*128*16)*4 ≈ 119.7 MB

    k_detect<<<1, 64, 0, stream>>>((const unsigned short*)d_in[0], flag);
    k_prep<<<1, 256, 0, stream>>>(d_in[1], d_in[2], d_in[3], d_in[4], d_in[5],
                                  d_in[6], d_in[7], d_in[8], d_in[9], wf, flag);
    k_qkv<<<NP / 256, 256, 0, stream>>>(d_in[0], wf, flag, qws2, ekws, vws);
    k_lamc<<<dim3(NCHUNK, BB), 256, 0, stream>>>(ekws, vws, Mpart, Spart);
    k_reduce<<<dim3(8, BB), 256, 0, stream>>>(Mpart, Spart, wf + M_OFF, wf + S_OFF);
    k_out<<<dim3(2 * HH, BB), 256, 0, stream>>>(qws2, vws, wf, wf + S_OFF, wf + M_OFF,
                                                flag, d_out);
}